// Round 4
// baseline (144.924 us; speedup 1.0000x reference)
//
#include <hip/hip_runtime.h>
#include <math.h>

// Problem constants (match reference)
#define Lp 1024
#define Bp 64
#define Tt 128          // tile rows
#define NTILE 8         // Lp / Tt
#define NPAIR 36        // NTILE*(NTILE+1)/2 triangular tile pairs
#define REP 8           // DIAGNOSTIC: repeat compute phase 8x (result scaled by 1/8)

typedef float v2 __attribute__((ext_vector_type(2)));
static __device__ __forceinline__ v2 splat2(float s) { v2 r; r.x = s; r.y = s; return r; }
static __device__ __forceinline__ v2 lo2(float4 v)   { v2 r; r.x = v.x; r.y = v.y; return r; }
static __device__ __forceinline__ v2 hi2(float4 v)   { v2 r; r.x = v.z; r.y = v.w; return r; }

// Identity: sum_{pairs} mi*mj*(dx-dy)^2
//         = sum mi*mj*(d2x+d2y)  -  2*sum mi*mj*dx*dy
// First term has an O(L) closed form via moments; the O(L^2) kernel only
// accumulates the cross term sqrt(d2x*d2y). Subtract-form d2 is >= 0 exactly.
//
// grid = (Bp, NPAIR+1): p < NPAIR  -> triangular tile-pair cross-term block
//                       p == NPAIR -> per-batch moment block (O(L) reductions)
__global__ __launch_bounds__(256) void drmsd_main(
    const float* __restrict__ x, const float* __restrict__ y,
    float* __restrict__ partials, float* __restrict__ moments)
{
    __shared__ __align__(16) float xsx[2][Tt], xsy[2][Tt], xsz[2][Tt];
    __shared__ __align__(16) float ysx[2][Tt], ysy[2][Tt], ysz[2][Tt];
    __shared__ __align__(16) float ms[2][Tt];
    __shared__ float red[4];
    __shared__ float mred[4][9];

    const int b = blockIdx.x;      // batch
    const int p = blockIdx.y;      // pair index 0..35, or 36 = moment block
    const int t = threadIdx.x;

    if (p == NPAIR) {
        // ---- moment block: Sx(3), Qx, Sy(3), Qy, M for batch b ----
        float v[9];
#pragma unroll
        for (int k = 0; k < 9; ++k) v[k] = 0.0f;
#pragma unroll
        for (int k = 0; k < 4; ++k) {
            const int row = t + k * 256;
            const float* px = x + (size_t)row * (Bp * 3) + (size_t)b * 3;
            const float* py = y + (size_t)row * (Bp * 3) + (size_t)b * 3;
            const float x0 = px[0], x1 = px[1], x2 = px[2];
            const float y0 = py[0], y1 = py[1], y2 = py[2];
            const float m = ((y0 + y1 + y2) != 0.0f) ? 1.0f : 0.0f;
            v[0] += m * x0; v[1] += m * x1; v[2] += m * x2;
            v[3] = fmaf(m, fmaf(x0, x0, fmaf(x1, x1, x2 * x2)), v[3]);
            v[4] += m * y0; v[5] += m * y1; v[6] += m * y2;
            v[7] = fmaf(m, fmaf(y0, y0, fmaf(y1, y1, y2 * y2)), v[7]);
            v[8] += m;
        }
#pragma unroll
        for (int k = 0; k < 9; ++k) {
#pragma unroll
            for (int off = 32; off > 0; off >>= 1)
                v[k] += __shfl_down(v[k], off, 64);
        }
        const int wave = t >> 6;
        if ((t & 63) == 0) {
#pragma unroll
            for (int k = 0; k < 9; ++k) mred[wave][k] = v[k];
        }
        __syncthreads();
        if (t < 9)
            moments[(size_t)b * 9 + t] =
                mred[0][t] + mred[1][t] + mred[2][t] + mred[3][t];
        return;
    }

    // decode p -> (ti, tj), ti <= tj
    int ti = 0, base = 0;
    while (p >= base + (NTILE - ti)) { base += (NTILE - ti); ++ti; }
    const int tj = ti + (p - base);

    // ---- stage: threads 0-127 -> i-tile (slot 0), 128-255 -> j-tile (slot 1)
    {
        const int r     = t & (Tt - 1);
        const int which = t >> 7;
        const int tile  = which ? tj : ti;
        const int row   = tile * Tt + r;
        const float* px = x + (size_t)row * (Bp * 3) + (size_t)b * 3;
        const float* py = y + (size_t)row * (Bp * 3) + (size_t)b * 3;
        const float x0 = px[0], x1 = px[1], x2 = px[2];
        const float y0 = py[0], y1 = py[1], y2 = py[2];
        xsx[which][r] = x0; xsy[which][r] = x1; xsz[which][r] = x2;
        ysx[which][r] = y0; ysy[which][r] = y1; ysz[which][r] = y2;
        ms[which][r]  = ((y0 + y1 + y2) != 0.0f) ? 1.0f : 0.0f;
    }
    __syncthreads();

    const int jc = (t & 15) << 2;     // first of 4 adjacent j columns
    const int rg = t >> 4;            // 0..15

    float total = 0.0f;
    int zero = 0;                     // opaque 0: forces per-rep recompute

#pragma unroll 1
    for (int rep = 0; rep < REP; ++rep) {
        asm volatile("" : "+v"(zero));  // compiler can't prove zero==0

#pragma unroll
        for (int half = 0; half < 2; ++half) {
            const int i0 = half * 64 + rg * 4 + zero;
            const float4 v_xx = *(const float4*)&xsx[0][i0];
            const float4 v_xy = *(const float4*)&xsy[0][i0];
            const float4 v_xz = *(const float4*)&xsz[0][i0];
            const float4 v_yx = *(const float4*)&ysx[0][i0];
            const float4 v_yy = *(const float4*)&ysy[0][i0];
            const float4 v_yz = *(const float4*)&ysz[0][i0];
            const float4 v_mi = *(const float4*)&ms[0][i0];
            const float xix[4] = { v_xx.x, v_xx.y, v_xx.z, v_xx.w };
            const float xiy[4] = { v_xy.x, v_xy.y, v_xy.z, v_xy.w };
            const float xiz[4] = { v_xz.x, v_xz.y, v_xz.z, v_xz.w };
            const float yix[4] = { v_yx.x, v_yx.y, v_yx.z, v_yx.w };
            const float yiy[4] = { v_yy.x, v_yy.y, v_yy.z, v_yy.w };
            const float yiz[4] = { v_yz.x, v_yz.y, v_yz.z, v_yz.w };
            const float mir[4] = { v_mi.x, v_mi.y, v_mi.z, v_mi.w };

            v2 acc[4];
#pragma unroll
            for (int r = 0; r < 4; ++r) acc[r] = splat2(0.0f);

#pragma unroll
            for (int jj = 0; jj < 2; ++jj) {
                const int j0 = jj * 64 + jc + zero;
                const float4 xjx4 = *(const float4*)&xsx[1][j0];
                const float4 xjy4 = *(const float4*)&xsy[1][j0];
                const float4 xjz4 = *(const float4*)&xsz[1][j0];
                const float4 yjx4 = *(const float4*)&ysx[1][j0];
                const float4 yjy4 = *(const float4*)&ysy[1][j0];
                const float4 yjz4 = *(const float4*)&ysz[1][j0];
                const float4 mj4  = *(const float4*)&ms[1][j0];
#pragma unroll
                for (int s = 0; s < 2; ++s) {
                    const v2 xjx = s ? hi2(xjx4) : lo2(xjx4);
                    const v2 xjy = s ? hi2(xjy4) : lo2(xjy4);
                    const v2 xjz = s ? hi2(xjz4) : lo2(xjz4);
                    const v2 yjx = s ? hi2(yjx4) : lo2(yjx4);
                    const v2 yjy = s ? hi2(yjy4) : lo2(yjy4);
                    const v2 yjz = s ? hi2(yjz4) : lo2(yjz4);
                    const v2 mj  = s ? hi2(mj4)  : lo2(mj4);
#pragma unroll
                    for (int r = 0; r < 4; ++r) {
                        const v2 ax = splat2(xix[r]) - xjx;
                        const v2 ay = splat2(xiy[r]) - xjy;
                        const v2 az = splat2(xiz[r]) - xjz;
                        const v2 d2x = ax * ax + ay * ay + az * az;  // pk_fma
                        const v2 bx = splat2(yix[r]) - yjx;
                        const v2 by = splat2(yiy[r]) - yjy;
                        const v2 bz = splat2(yiz[r]) - yjz;
                        const v2 d2y = bx * bx + by * by + bz * bz;
                        const v2 pr = d2x * d2y;                     // >= 0 exactly
                        v2 sq;
                        sq.x = __builtin_amdgcn_sqrtf(pr.x);
                        sq.y = __builtin_amdgcn_sqrtf(pr.y);
                        acc[r] = mj * sq + acc[r];                   // col mask, pk_fma
                    }
                }
            }
#pragma unroll
            for (int r = 0; r < 4; ++r)
                total = fmaf(acc[r].x + acc[r].y, mir[r], total);    // row mask
        }
    }
    total *= 0.125f;   // 1/REP, exact power of 2

    // ---- block reduction ----
#pragma unroll
    for (int off = 32; off > 0; off >>= 1)
        total += __shfl_down(total, off, 64);
    const int wave = t >> 6;
    if ((t & 63) == 0) red[wave] = total;
    __syncthreads();
    if (t == 0) {
        float s = red[0] + red[1] + red[2] + red[3];
        if (ti != tj) s *= 2.0f;   // off-diagonal pair counted for both orders
        partials[(size_t)p * Bp + b] = s;   // [p][b] layout -> coalesced final
    }
}

// Single wave: combine closed-form (d2x+d2y) term with cross-term partials.
__global__ __launch_bounds__(64) void drmsd_final(
    const float* __restrict__ partials, const float* __restrict__ moments,
    float* __restrict__ out)
{
    const int b = threadIdx.x;   // 0..63, one batch per lane
    double cross = 0.0;
#pragma unroll
    for (int pp = 0; pp < NPAIR; ++pp)
        cross += (double)partials[(size_t)pp * Bp + b];   // coalesced

    const float* mo = moments + (size_t)b * 9;
    const double sx0 = mo[0], sx1 = mo[1], sx2 = mo[2], qx = mo[3];
    const double sy0 = mo[4], sy1 = mo[5], sy2 = mo[6], qy = mo[7];
    const double M   = mo[8];
    const double term1 = 2.0 * M * (qx + qy)
        - 2.0 * (sx0*sx0 + sx1*sx1 + sx2*sx2 + sy0*sy0 + sy1*sy1 + sy2*sy2);

    double su = term1 - 2.0 * cross;
    su = su > 0.0 ? su : 0.0;        // guard rounding when x == y
    double pb = sqrt(su);
#pragma unroll
    for (int off = 32; off > 0; off >>= 1)
        pb += __shfl_down(pb, off, 64);
    if (b == 0) {
        const double denom = sqrt((double)Lp * (double)Lp / 2.0 - (double)Lp);
        out[0] = (float)(pb / denom / (double)Bp);
    }
}

extern "C" void kernel_launch(void* const* d_in, const int* in_sizes, int n_in,
                              void* d_out, int out_size, void* d_ws, size_t ws_size,
                              hipStream_t stream) {
    const float* x = (const float*)d_in[0];
    const float* y = (const float*)d_in[1];
    float* out      = (float*)d_out;
    float* partials = (float*)d_ws;                   // NPAIR*Bp floats
    float* moments  = partials + NPAIR * Bp;          // Bp*9 floats (total < 12 KB)

    dim3 grid(Bp, NPAIR + 1);
    drmsd_main<<<grid, 256, 0, stream>>>(x, y, partials, moments);
    drmsd_final<<<1, 64, 0, stream>>>(partials, moments, out);
}

// Round 5
// 68.743 us; speedup vs baseline: 2.1082x; 2.1082x over previous
//
#include <hip/hip_runtime.h>
#include <math.h>

// Problem constants (match reference)
#define Lp 1024
#define Bp 64
#define Tt 128          // tile rows
#define NTILE 8         // Lp / Tt
#define NPAIR 36        // NTILE*(NTILE+1)/2 triangular tile pairs

typedef float v2 __attribute__((ext_vector_type(2)));
static __device__ __forceinline__ v2 splat2(float s) { v2 r; r.x = s; r.y = s; return r; }
static __device__ __forceinline__ v2 lo2(float4 v)   { v2 r; r.x = v.x; r.y = v.y; return r; }
static __device__ __forceinline__ v2 hi2(float4 v)   { v2 r; r.x = v.z; r.y = v.w; return r; }

// Identity: sum_{pairs} mi*mj*(dx-dy)^2
//         = sum mi*mj*(d2x+d2y)  -  2*sum mi*mj*dx*dy   (first term O(L) via moments)
// Cross term per pair: d2x = -2*ux, ux = xi.xj - |xi|^2/2 - |xj|^2/2  (ux <= 0 exact)
//   sqrt(d2x*d2y) = 2*sqrt(ux*uy); the 2 is folded into the block-partial scale.
// ux costs 4 fp32 ops (1 add + 3 fma) vs 6 for the subtract form; sqrt(|pr|)
// uses the free VOP3 abs modifier instead of a clamp. 10 VALU + 1 trans / pair
// (was 14 + 1) -- the kernel is fp32-execution-bound (R4: VALUBusy 80%).
//
// grid = (Bp, NPAIR+1): p < NPAIR  -> triangular tile-pair cross-term block
//                       p == NPAIR -> per-batch moment block (O(L) reductions)
__global__ __launch_bounds__(256) void drmsd_main(
    const float* __restrict__ x, const float* __restrict__ y,
    float* __restrict__ partials, float* __restrict__ moments)
{
    __shared__ __align__(16) float xsx[2][Tt], xsy[2][Tt], xsz[2][Tt];
    __shared__ __align__(16) float ysx[2][Tt], ysy[2][Tt], ysz[2][Tt];
    __shared__ __align__(16) float nhx[2][Tt], nhy[2][Tt];   // -|x|^2/2, -|y|^2/2
    __shared__ __align__(16) float ms[2][Tt];
    __shared__ float red[4];
    __shared__ float mred[4][9];

    const int b = blockIdx.x;      // batch
    const int p = blockIdx.y;      // pair index 0..35, or 36 = moment block
    const int t = threadIdx.x;

    if (p == NPAIR) {
        // ---- moment block: Sx(3), Qx, Sy(3), Qy, M for batch b ----
        float v[9];
#pragma unroll
        for (int k = 0; k < 9; ++k) v[k] = 0.0f;
#pragma unroll
        for (int k = 0; k < 4; ++k) {
            const int row = t + k * 256;
            const float* px = x + (size_t)row * (Bp * 3) + (size_t)b * 3;
            const float* py = y + (size_t)row * (Bp * 3) + (size_t)b * 3;
            const float x0 = px[0], x1 = px[1], x2 = px[2];
            const float y0 = py[0], y1 = py[1], y2 = py[2];
            const float m = ((y0 + y1 + y2) != 0.0f) ? 1.0f : 0.0f;
            v[0] += m * x0; v[1] += m * x1; v[2] += m * x2;
            v[3] = fmaf(m, fmaf(x0, x0, fmaf(x1, x1, x2 * x2)), v[3]);
            v[4] += m * y0; v[5] += m * y1; v[6] += m * y2;
            v[7] = fmaf(m, fmaf(y0, y0, fmaf(y1, y1, y2 * y2)), v[7]);
            v[8] += m;
        }
#pragma unroll
        for (int k = 0; k < 9; ++k) {
#pragma unroll
            for (int off = 32; off > 0; off >>= 1)
                v[k] += __shfl_down(v[k], off, 64);
        }
        const int wave = t >> 6;
        if ((t & 63) == 0) {
#pragma unroll
            for (int k = 0; k < 9; ++k) mred[wave][k] = v[k];
        }
        __syncthreads();
        if (t < 9)
            moments[(size_t)b * 9 + t] =
                mred[0][t] + mred[1][t] + mred[2][t] + mred[3][t];
        return;
    }

    // decode p -> (ti, tj), ti <= tj
    int ti = 0, base = 0;
    while (p >= base + (NTILE - ti)) { base += (NTILE - ti); ++ti; }
    const int tj = ti + (p - base);

    // ---- stage: threads 0-127 -> i-tile (slot 0), 128-255 -> j-tile (slot 1)
    {
        const int r     = t & (Tt - 1);
        const int which = t >> 7;
        const int tile  = which ? tj : ti;
        const int row   = tile * Tt + r;
        const float* px = x + (size_t)row * (Bp * 3) + (size_t)b * 3;
        const float* py = y + (size_t)row * (Bp * 3) + (size_t)b * 3;
        const float x0 = px[0], x1 = px[1], x2 = px[2];
        const float y0 = py[0], y1 = py[1], y2 = py[2];
        xsx[which][r] = x0; xsy[which][r] = x1; xsz[which][r] = x2;
        ysx[which][r] = y0; ysy[which][r] = y1; ysz[which][r] = y2;
        nhx[which][r] = -0.5f * fmaf(x0, x0, fmaf(x1, x1, x2 * x2));
        nhy[which][r] = -0.5f * fmaf(y0, y0, fmaf(y1, y1, y2 * y2));
        ms[which][r]  = ((y0 + y1 + y2) != 0.0f) ? 1.0f : 0.0f;
    }
    __syncthreads();

    const int jc = (t & 15) << 2;     // first of 4 adjacent j columns
    const int rg = t >> 4;            // 0..15

    float total = 0.0f;

#pragma unroll
    for (int half = 0; half < 2; ++half) {
        const int i0 = half * 64 + rg * 4;
        const float4 v_xx = *(const float4*)&xsx[0][i0];
        const float4 v_xy = *(const float4*)&xsy[0][i0];
        const float4 v_xz = *(const float4*)&xsz[0][i0];
        const float4 v_yx = *(const float4*)&ysx[0][i0];
        const float4 v_yy = *(const float4*)&ysy[0][i0];
        const float4 v_yz = *(const float4*)&ysz[0][i0];
        const float4 v_hx = *(const float4*)&nhx[0][i0];
        const float4 v_hy = *(const float4*)&nhy[0][i0];
        const float4 v_mi = *(const float4*)&ms[0][i0];
        const float xix[4] = { v_xx.x, v_xx.y, v_xx.z, v_xx.w };
        const float xiy[4] = { v_xy.x, v_xy.y, v_xy.z, v_xy.w };
        const float xiz[4] = { v_xz.x, v_xz.y, v_xz.z, v_xz.w };
        const float yix[4] = { v_yx.x, v_yx.y, v_yx.z, v_yx.w };
        const float yiy[4] = { v_yy.x, v_yy.y, v_yy.z, v_yy.w };
        const float yiz[4] = { v_yz.x, v_yz.y, v_yz.z, v_yz.w };
        const float hxi[4] = { v_hx.x, v_hx.y, v_hx.z, v_hx.w };
        const float hyi[4] = { v_hy.x, v_hy.y, v_hy.z, v_hy.w };
        const float mir[4] = { v_mi.x, v_mi.y, v_mi.z, v_mi.w };

        v2 acc[4];
#pragma unroll
        for (int r = 0; r < 4; ++r) acc[r] = splat2(0.0f);

#pragma unroll
        for (int jj = 0; jj < 2; ++jj) {
            const int j0 = jj * 64 + jc;
            const float4 xjx4 = *(const float4*)&xsx[1][j0];
            const float4 xjy4 = *(const float4*)&xsy[1][j0];
            const float4 xjz4 = *(const float4*)&xsz[1][j0];
            const float4 yjx4 = *(const float4*)&ysx[1][j0];
            const float4 yjy4 = *(const float4*)&ysy[1][j0];
            const float4 yjz4 = *(const float4*)&ysz[1][j0];
            const float4 hxj4 = *(const float4*)&nhx[1][j0];
            const float4 hyj4 = *(const float4*)&nhy[1][j0];
            const float4 mj4  = *(const float4*)&ms[1][j0];
#pragma unroll
            for (int s = 0; s < 2; ++s) {
                const v2 xjx = s ? hi2(xjx4) : lo2(xjx4);
                const v2 xjy = s ? hi2(xjy4) : lo2(xjy4);
                const v2 xjz = s ? hi2(xjz4) : lo2(xjz4);
                const v2 yjx = s ? hi2(yjx4) : lo2(yjx4);
                const v2 yjy = s ? hi2(yjy4) : lo2(yjy4);
                const v2 yjz = s ? hi2(yjz4) : lo2(yjz4);
                const v2 hxj = s ? hi2(hxj4) : lo2(hxj4);
                const v2 hyj = s ? hi2(hyj4) : lo2(hyj4);
                const v2 mj  = s ? hi2(mj4)  : lo2(mj4);
#pragma unroll
                for (int r = 0; r < 4; ++r) {
                    // ux = xi.xj - |xi|^2/2 - |xj|^2/2  (<= 0 in exact math)
                    v2 ux = splat2(hxi[r]) + hxj;                 // 1 add
                    ux = splat2(xix[r]) * xjx + ux;               // 3 fma
                    ux = splat2(xiy[r]) * xjy + ux;
                    ux = splat2(xiz[r]) * xjz + ux;
                    v2 uy = splat2(hyi[r]) + hyj;
                    uy = splat2(yix[r]) * yjx + uy;
                    uy = splat2(yiy[r]) * yjy + uy;
                    uy = splat2(yiz[r]) * yjz + uy;
                    const v2 pr = ux * uy;                        // >= 0 up to rounding
                    v2 sq;                                        // |.| folds into VOP3 mod
                    sq.x = __builtin_amdgcn_sqrtf(__builtin_fabsf(pr.x));
                    sq.y = __builtin_amdgcn_sqrtf(__builtin_fabsf(pr.y));
                    acc[r] = mj * sq + acc[r];                    // col mask, fma
                }
            }
        }
#pragma unroll
        for (int r = 0; r < 4; ++r)
            total = fmaf(acc[r].x + acc[r].y, mir[r], total);     // row mask
    }

    // ---- block reduction ----
#pragma unroll
    for (int off = 32; off > 0; off >>= 1)
        total += __shfl_down(total, off, 64);
    const int wave = t >> 6;
    if ((t & 63) == 0) red[wave] = total;
    __syncthreads();
    if (t == 0) {
        float s = red[0] + red[1] + red[2] + red[3];
        // x2: sqrt(d2x*d2y) = 2*sqrt(ux*uy); extra x2 off-diag for both orders
        s *= (ti != tj) ? 4.0f : 2.0f;
        partials[(size_t)p * Bp + b] = s;   // [p][b] layout -> coalesced final
    }
}

// Single wave: combine closed-form (d2x+d2y) term with cross-term partials.
__global__ __launch_bounds__(64) void drmsd_final(
    const float* __restrict__ partials, const float* __restrict__ moments,
    float* __restrict__ out)
{
    const int b = threadIdx.x;   // 0..63, one batch per lane
    double cross = 0.0;
#pragma unroll
    for (int pp = 0; pp < NPAIR; ++pp)
        cross += (double)partials[(size_t)pp * Bp + b];   // coalesced

    const float* mo = moments + (size_t)b * 9;
    const double sx0 = mo[0], sx1 = mo[1], sx2 = mo[2], qx = mo[3];
    const double sy0 = mo[4], sy1 = mo[5], sy2 = mo[6], qy = mo[7];
    const double M   = mo[8];
    const double term1 = 2.0 * M * (qx + qy)
        - 2.0 * (sx0*sx0 + sx1*sx1 + sx2*sx2 + sy0*sy0 + sy1*sy1 + sy2*sy2);

    double su = term1 - 2.0 * cross;
    su = su > 0.0 ? su : 0.0;        // guard rounding when x == y
    double pb = sqrt(su);
#pragma unroll
    for (int off = 32; off > 0; off >>= 1)
        pb += __shfl_down(pb, off, 64);
    if (b == 0) {
        const double denom = sqrt((double)Lp * (double)Lp / 2.0 - (double)Lp);
        out[0] = (float)(pb / denom / (double)Bp);
    }
}

extern "C" void kernel_launch(void* const* d_in, const int* in_sizes, int n_in,
                              void* d_out, int out_size, void* d_ws, size_t ws_size,
                              hipStream_t stream) {
    const float* x = (const float*)d_in[0];
    const float* y = (const float*)d_in[1];
    float* out      = (float*)d_out;
    float* partials = (float*)d_ws;                   // NPAIR*Bp floats
    float* moments  = partials + NPAIR * Bp;          // Bp*9 floats (total < 12 KB)

    dim3 grid(Bp, NPAIR + 1);
    drmsd_main<<<grid, 256, 0, stream>>>(x, y, partials, moments);
    drmsd_final<<<1, 64, 0, stream>>>(partials, moments, out);
}